// Round 1
// baseline (1743.722 us; speedup 1.0000x reference)
//
#include <hip/hip_runtime.h>
#include <math.h>

// Problem geometry (fixed by setup_inputs): B=16, C=1, H=W=1024, f32.
#define H_IMG 1024
#define W_IMG 1024
#define N_B   16
#define NPIX  (H_IMG * W_IMG)
#define N_TOT (N_B * NPIX)

#define TILE 32
#define REG  36   // TILE + 2*halo, halo = 2 (one erode + one dilate)

__device__ __forceinline__ float sigm(float x) { return 1.0f / (1.0f + __expf(-x)); }

// ---------------------------------------------------------------------------
// One fused skeletonization step.
//   reads  src = e_k  (or the source map when INIT)
//   computes e_{k+1} = erode(e_k)        (plus-shaped 5-point min)
//            open    = dilate(e_{k+1})   (3x3 max)
//            delta   = relu(e_k - open)
//   INIT:  skel = delta        else: skel += relu(delta - skel*delta)
//   WRITE_ER: er_out = e_{k+1}
// Border rule: reduce_window with +/-inf identity == op over valid pixels.
// Clamp loads are exact for ONE pass; the fused second pass (dilate) must
// see -inf at out-of-image erode positions (phantom values would corrupt max).
// ---------------------------------------------------------------------------
template<bool SRC_SIGMOID, bool INIT, bool WRITE_ER>
__global__ __launch_bounds__(256)
void skel_step(const float* __restrict__ src,
               float* __restrict__ er_out,
               float* __restrict__ skel)
{
    __shared__ float A[REG * REG];   // source region, halo 2, clamped loads
    __shared__ float Bs[REG * REG];  // erode(A) on the halo-1 ring
    const int b   = blockIdx.z;
    const int r0  = blockIdx.y * TILE;
    const int c0  = blockIdx.x * TILE;
    const int tid = threadIdx.y * 32 + threadIdx.x;   // block (32,8)
    const float* s = src + (size_t)b * NPIX;

    // ---- load region [r0-2, r0+34) x [c0-2, c0+34), clamped to image ----
    for (int i = tid; i < REG * REG; i += 256) {
        const int rr = i / REG, cc = i - rr * REG;
        const int gr = min(max(r0 - 2 + rr, 0), H_IMG - 1);
        const int gc = min(max(c0 - 2 + cc, 0), W_IMG - 1);
        float v = s[gr * W_IMG + gc];
        if (SRC_SIGMOID) v = sigm(v);
        A[i] = v;
    }
    __syncthreads();

    // ---- erode on the radius-1 region [1,35)^2 ----
    for (int i = tid; i < 34 * 34; i += 256) {
        const int rr = 1 + i / 34;
        const int cc = 1 + (i - (i / 34) * 34);
        const int gr = r0 - 2 + rr, gc = c0 - 2 + cc;
        const int idx = rr * REG + cc;
        float v;
        if (gr < 0 || gr >= H_IMG || gc < 0 || gc >= W_IMG) {
            v = -INFINITY;  // out-of-image erode output must not win the dilate max
        } else {
            v = fminf(fminf(A[idx], A[idx - REG]),
                      fminf(A[idx + REG], fminf(A[idx - 1], A[idx + 1])));
        }
        Bs[idx] = v;
    }
    __syncthreads();

    // ---- per owned pixel: dilate, delta, skel update, er_out ----
    for (int yy = threadIdx.y; yy < TILE; yy += 8) {
        const int rr = 2 + yy, cc = 2 + threadIdx.x;
        const int idx = rr * REG + cc;
        const float m0 = fmaxf(fmaxf(Bs[idx - REG - 1], Bs[idx - REG]), Bs[idx - REG + 1]);
        const float m1 = fmaxf(fmaxf(Bs[idx - 1],       Bs[idx]      ), Bs[idx + 1]);
        const float m2 = fmaxf(fmaxf(Bs[idx + REG - 1], Bs[idx + REG]), Bs[idx + REG + 1]);
        const float open_v = fmaxf(fmaxf(m0, m1), m2);
        const float er_c   = A[idx];
        const float delta  = fmaxf(er_c - open_v, 0.0f);
        const size_t g = (size_t)b * NPIX + (size_t)(r0 + yy) * W_IMG + (c0 + threadIdx.x);
        if (INIT) {
            skel[g] = delta;
        } else {
            const float s0 = skel[g];
            skel[g] = s0 + fmaxf(delta - s0 * delta, 0.0f);
        }
        if (WRITE_ER) er_out[g] = Bs[idx];
    }
}

// ---------------------------------------------------------------------------
// Reductions: per-thread f32 partials -> per-block f64 tree -> f64 atomic.
// ---------------------------------------------------------------------------
__device__ void block_add(double v, double* dst) {
    __shared__ double sm[256];
    const int tid = threadIdx.x;
    sm[tid] = v;
    __syncthreads();
    for (int s = 128; s > 0; s >>= 1) {
        if (tid < s) sm[tid] += sm[tid + s];
        __syncthreads();
    }
    if (tid == 0) atomicAdd(dst, sm[0]);
    __syncthreads();
}

__global__ __launch_bounds__(256)
void bce_dice_reduce(const float4* __restrict__ p4, const float4* __restrict__ t4,
                     double* __restrict__ acc)
{
    float sb = 0.f, sp = 0.f, sy = 0.f, spy = 0.f;
    const int n4 = N_TOT / 4;
    for (int i = blockIdx.x * 256 + threadIdx.x; i < n4; i += gridDim.x * 256) {
        const float4 x4 = p4[i];
        const float4 y4 = t4[i];
        const float xs[4] = {x4.x, x4.y, x4.z, x4.w};
        const float ys[4] = {y4.x, y4.y, y4.z, y4.w};
#pragma unroll
        for (int k = 0; k < 4; ++k) {
            const float x = xs[k], y = ys[k];
            const float p = sigm(x);
            // BCEWithLogits per-pixel: softplus(x) - y*x  (stable)
            sb += fmaxf(x, 0.0f) + log1pf(__expf(-fabsf(x))) - y * x;
            sp += p; sy += y; spy += p * y;
        }
    }
    block_add((double)sb,  acc + 0);
    block_add((double)sp,  acc + 1);
    block_add((double)sy,  acc + 2);
    block_add((double)spy, acc + 3);
}

template<bool OTH_SIG>
__global__ __launch_bounds__(256)
void skel_reduce(const float4* __restrict__ sk4, const float4* __restrict__ ot4,
                 double* __restrict__ acc2)
{
    float ss = 0.f, sso = 0.f;
    const int n4 = N_TOT / 4;
    for (int i = blockIdx.x * 256 + threadIdx.x; i < n4; i += gridDim.x * 256) {
        const float4 s4 = sk4[i];
        const float4 o4 = ot4[i];
        const float sv[4] = {s4.x, s4.y, s4.z, s4.w};
        const float ov[4] = {o4.x, o4.y, o4.z, o4.w};
#pragma unroll
        for (int k = 0; k < 4; ++k) {
            const float o = OTH_SIG ? sigm(ov[k]) : ov[k];
            ss  += sv[k];
            sso += sv[k] * o;
        }
    }
    block_add((double)ss,  acc2 + 0);
    block_add((double)sso, acc2 + 1);
}

__global__ void zero_acc(double* acc) {
    if (threadIdx.x < 8) acc[threadIdx.x] = 0.0;
}

__global__ void finalize_k(const double* __restrict__ acc, float* __restrict__ out)
{
    const double bce   = acc[0] / (double)N_TOT;
    const double dice  = (2.0 * acc[3] + 1.0) / (acc[1] + acc[2] + 1.0);
    const double tprec = (acc[5] + 1.0) / (acc[4] + 1.0);
    const double tsens = (acc[7] + 1.0) / (acc[6] + 1.0);
    const double cl    = 2.0 * tprec * tsens / (tprec + tsens + 1e-7);
    out[0] = (float)(0.3 * bce + 0.3 * (1.0 - dice) + 0.4 * (1.0 - cl));
}

// ---------------------------------------------------------------------------
extern "C" void kernel_launch(void* const* d_in, const int* in_sizes, int n_in,
                              void* d_out, int out_size, void* d_ws, size_t ws_size,
                              hipStream_t stream)
{
    const float* pred = (const float*)d_in[0];
    const float* tgt  = (const float*)d_in[1];
    float* out = (float*)d_out;

    char* ws = (char*)d_ws;
    double* acc  = (double*)ws;                 // 8 scalars
    float*  er_a = (float*)(ws + 256);
    float*  er_b = er_a + N_TOT;
    float*  skel = er_b + N_TOT;                // total ~192 MB + 256 B

    zero_acc<<<1, 64, 0, stream>>>(acc);

    bce_dice_reduce<<<4096, 256, 0, stream>>>((const float4*)pred, (const float4*)tgt, acc);

    const dim3 grid(W_IMG / TILE, H_IMG / TILE, N_B);
    const dim3 block(32, 8);

    // ---- skeleton of p = sigmoid(pred) ----
    skel_step<true, true, true><<<grid, block, 0, stream>>>(pred, er_a, skel);
    {
        float* pin = er_a; float* pout = er_b;
        for (int i = 1; i <= 10; ++i) {
            if (i < 10) skel_step<false, false, true ><<<grid, block, 0, stream>>>(pin, pout, skel);
            else        skel_step<false, false, false><<<grid, block, 0, stream>>>(pin, pout, skel);
            float* t = pin; pin = pout; pout = t;
        }
    }
    skel_reduce<false><<<4096, 256, 0, stream>>>((const float4*)skel, (const float4*)tgt, acc + 4);

    // ---- skeleton of target ----
    skel_step<false, true, true><<<grid, block, 0, stream>>>(tgt, er_a, skel);
    {
        float* pin = er_a; float* pout = er_b;
        for (int i = 1; i <= 10; ++i) {
            if (i < 10) skel_step<false, false, true ><<<grid, block, 0, stream>>>(pin, pout, skel);
            else        skel_step<false, false, false><<<grid, block, 0, stream>>>(pin, pout, skel);
            float* t = pin; pin = pout; pout = t;
        }
    }
    skel_reduce<true><<<4096, 256, 0, stream>>>((const float4*)skel, (const float4*)pred, acc + 6);

    finalize_k<<<1, 1, 0, stream>>>(acc, out);
}

// Round 2
// 790.034 us; speedup vs baseline: 2.2071x; 2.2071x over previous
//
#include <hip/hip_runtime.h>
#include <math.h>

// Geometry (fixed): B=16, C=1, H=W=1024, f32.
#define H_IMG 1024
#define W_IMG 1024
#define N_B   16
#define NPIX  (H_IMG * W_IMG)
#define N_TOT (N_B * NPIX)

// Mega-kernel tiling: 64x64 owned tile, halo 12 (11 fused erode iters + 1 dilate ring).
#define TILE   64
#define HALO   12
#define RG     88          // TILE + 2*HALO
#define RST    92          // padded LDS row stride (floats); 92*4 B = 368 B, 16B-aligned
#define NSTRIP 22          // RG / 4

#define SLOTS  32          // atomic accumulator slots (each its own 64B line)

__device__ __forceinline__ float sigm(float x)  { return 1.0f / (1.0f + __expf(-x)); }
__device__ __forceinline__ float min3f(float a, float b, float c) { return fminf(fminf(a, b), c); }
__device__ __forceinline__ float max3f(float a, float b, float c) { return fmaxf(fmaxf(a, b), c); }

// Overwrite region cells whose GLOBAL coords fall outside the image.
// Erode input needs +INF there (min identity); dilate input needs -INF (max identity).
__device__ __forceinline__ void band_fix(float* b, float val, int r0, int c0, int tid)
{
    if (r0 == 0) {
        for (int idx = tid; idx < HALO * RG; idx += 512) {
            const int r = idx / RG, c = idx - r * RG;
            b[r * RST + c] = val;
        }
    }
    if (r0 == H_IMG - TILE) {
        for (int idx = tid; idx < HALO * RG; idx += 512) {
            const int r = idx / RG, c = idx - r * RG;
            b[(RG - HALO + r) * RST + c] = val;
        }
    }
    if (c0 == 0) {
        for (int idx = tid; idx < RG * HALO; idx += 512) {
            const int r = idx / HALO, c = idx - r * HALO;
            b[r * RST + c] = val;
        }
    }
    if (c0 == W_IMG - TILE) {
        for (int idx = tid; idx < RG * HALO; idx += 512) {
            const int r = idx / HALO, c = idx - r * HALO;
            b[r * RST + (RG - HALO + c)] = val;
        }
    }
}

// ---------------------------------------------------------------------------
// Whole soft_skeleton (11 iterations) for one 64x64 tile, fully in LDS.
// Fuses the final  sum(skel), sum(skel*other)  reduction (skel never hits HBM).
//   iteration i: ernew = erode(er); [band fix]; open = dilate(ernew) at owned;
//                delta = relu(er - open); skel += relu(delta - skel*delta)  (skel0=0 trick)
// Validity: after erode_i, nxt valid on region margin >= i+1; dilate reads
// margin-11 ring (11 >= i+1 for i<=10). Garbage stays confined to margin < i+1.
// ---------------------------------------------------------------------------
template<bool SIG_SRC, bool SIG_OTH, int CBASE>
__global__ __launch_bounds__(512, 4)
void skel_mega(const float* __restrict__ src, const float* __restrict__ oth,
               double* __restrict__ acc)
{
    __shared__ __align__(16) float buf[2][RG * RST];
    __shared__ float rss[8], rsso[8];

    const int z   = blockIdx.z;
    const int r0  = blockIdx.y * TILE;
    const int c0  = blockIdx.x * TILE;
    const int tid = threadIdx.x;
    const float* s = src + (size_t)z * NPIX;

    float* cur = buf[0];
    float* nxt = buf[1];

    // ---- load 88x88 region (float4 strips; clamp rows always, cols on edge blocks) ----
    for (int idx = tid; idx < RG * NSTRIP; idx += 512) {
        const int q  = idx / NSTRIP;
        const int st = idx - q * NSTRIP;
        const int r  = q;
        const int c  = 4 * st;
        const int gr = min(max(r0 - HALO + r, 0), H_IMG - 1);
        const int gc = c0 - HALO + c;
        float4 v;
        if (gc >= 0 && gc + 3 < W_IMG) {
            v = *(const float4*)&s[(size_t)gr * W_IMG + gc];
        } else {
            v.x = s[(size_t)gr * W_IMG + min(max(gc + 0, 0), W_IMG - 1)];
            v.y = s[(size_t)gr * W_IMG + min(max(gc + 1, 0), W_IMG - 1)];
            v.z = s[(size_t)gr * W_IMG + min(max(gc + 2, 0), W_IMG - 1)];
            v.w = s[(size_t)gr * W_IMG + min(max(gc + 3, 0), W_IMG - 1)];
        }
        if (SIG_SRC) { v.x = sigm(v.x); v.y = sigm(v.y); v.z = sigm(v.z); v.w = sigm(v.w); }
        *(float4*)&cur[r * RST + c] = v;
    }
    __syncthreads();

    const bool edge = (r0 == 0) | (c0 == 0) | (r0 == H_IMG - TILE) | (c0 == W_IMG - TILE);

    float4 sk[2];
    sk[0] = make_float4(0.f, 0.f, 0.f, 0.f);
    sk[1] = make_float4(0.f, 0.f, 0.f, 0.f);

    const int oy = tid >> 3;      // owned row 0..63
    const int j  = tid & 7;       // strip slot 0..7 (strips j, j+8)
    const int rr = HALO + oy;     // region row of owned pixel

    for (int i = 0; i < 11; ++i) {
        if (edge) band_fix(cur, INFINITY, r0, c0, tid);
        __syncthreads();

        // ---- erode: rows [i+1, 87-i), all 22 col-strips (edge garbage confined) ----
        const int rlo   = i + 1;
        const int nrows = RG - 2 - 2 * i;   // 86 - 2i
        for (int idx = tid; idx < nrows * NSTRIP; idx += 512) {
            const int q  = idx / NSTRIP;
            const int st = idx - q * NSTRIP;
            const int r  = rlo + q;
            const int c  = 4 * st;
            const float4 mid = *(const float4*)&cur[r * RST + c];
            const float4 up  = *(const float4*)&cur[(r - 1) * RST + c];
            const float4 dn  = *(const float4*)&cur[(r + 1) * RST + c];
            const float  lf  = cur[r * RST + max(c - 1, 0)];
            const float  rt  = cur[r * RST + min(c + 4, RG - 1)];
            float4 e;
            e.x = min3f(min3f(up.x, mid.x, dn.x), lf,    mid.y);
            e.y = min3f(min3f(up.y, mid.y, dn.y), mid.x, mid.z);
            e.z = min3f(min3f(up.z, mid.z, dn.z), mid.y, mid.w);
            e.w = min3f(min3f(up.w, mid.w, dn.w), mid.z, rt);
            *(float4*)&nxt[r * RST + c] = e;
        }
        __syncthreads();

        if (edge) band_fix(nxt, -INFINITY, r0, c0, tid);
        __syncthreads();

        // ---- dilate(ernew) at owned pixels + skel update (2 strips/thread) ----
        #pragma unroll
        for (int t = 0; t < 2; ++t) {
            const int c = HALO + 4 * (j + 8 * t);
            const float4 a = *(const float4*)&nxt[(rr - 1) * RST + c];
            const float4 b = *(const float4*)&nxt[(rr    ) * RST + c];
            const float4 d = *(const float4*)&nxt[(rr + 1) * RST + c];
            const float aL = nxt[(rr - 1) * RST + c - 1], bL = nxt[rr * RST + c - 1], dL = nxt[(rr + 1) * RST + c - 1];
            const float aR = nxt[(rr - 1) * RST + c + 4], bR = nxt[rr * RST + c + 4], dR = nxt[(rr + 1) * RST + c + 4];
            const float vl = max3f(aL, bL, dL);
            const float v0 = max3f(a.x, b.x, d.x);
            const float v1 = max3f(a.y, b.y, d.y);
            const float v2 = max3f(a.z, b.z, d.z);
            const float v3 = max3f(a.w, b.w, d.w);
            const float vr = max3f(aR, bR, dR);
            const float4 e = *(const float4*)&cur[rr * RST + c];   // er_i (pre-erode center)
            const float o0 = max3f(vl, v0, v1);
            const float o1 = max3f(v0, v1, v2);
            const float o2 = max3f(v1, v2, v3);
            const float o3 = max3f(v2, v3, vr);
            float dd;
            dd = fmaxf(e.x - o0, 0.f); sk[t].x += fmaxf(dd - sk[t].x * dd, 0.f);
            dd = fmaxf(e.y - o1, 0.f); sk[t].y += fmaxf(dd - sk[t].y * dd, 0.f);
            dd = fmaxf(e.z - o2, 0.f); sk[t].z += fmaxf(dd - sk[t].z * dd, 0.f);
            dd = fmaxf(e.w - o3, 0.f); sk[t].w += fmaxf(dd - sk[t].w * dd, 0.f);
        }
        __syncthreads();

        float* tp = cur; cur = nxt; nxt = tp;
    }

    // ---- fused reduction: sum(skel), sum(skel * other) over owned pixels ----
    const float* op = oth + (size_t)z * NPIX + (size_t)(r0 + oy) * W_IMG + c0;
    float ss = 0.f, sso = 0.f;
    #pragma unroll
    for (int t = 0; t < 2; ++t) {
        float4 ov = *(const float4*)&op[4 * (j + 8 * t)];
        if (SIG_OTH) { ov.x = sigm(ov.x); ov.y = sigm(ov.y); ov.z = sigm(ov.z); ov.w = sigm(ov.w); }
        ss  += sk[t].x + sk[t].y + sk[t].z + sk[t].w;
        sso += sk[t].x * ov.x + sk[t].y * ov.y + sk[t].z * ov.z + sk[t].w * ov.w;
    }
    for (int off = 32; off > 0; off >>= 1) {
        ss  += __shfl_down(ss,  off);
        sso += __shfl_down(sso, off);
    }
    const int wid = tid >> 6, lane = tid & 63;
    if (lane == 0) { rss[wid] = ss; rsso[wid] = sso; }
    __syncthreads();
    if (tid == 0) {
        double SS = 0.0, SO = 0.0;
        for (int w = 0; w < 8; ++w) { SS += (double)rss[w]; SO += (double)rsso[w]; }
        const int bid  = (blockIdx.z * gridDim.y + blockIdx.y) * gridDim.x + blockIdx.x;
        const int slot = bid & (SLOTS - 1);
        atomicAdd(&acc[slot * 8 + CBASE],     SS);
        atomicAdd(&acc[slot * 8 + CBASE + 1], SO);
    }
}

// ---------------------------------------------------------------------------
// BCE + dice sums. Fast math (__expf/__logf), slot-spread f64 atomics.
// ---------------------------------------------------------------------------
__global__ __launch_bounds__(256)
void bce_dice_reduce(const float4* __restrict__ p4, const float4* __restrict__ t4,
                     double* __restrict__ acc)
{
    float sb = 0.f, sp = 0.f, sy = 0.f, spy = 0.f;
    const int n4 = N_TOT / 4;
    for (int i = blockIdx.x * 256 + threadIdx.x; i < n4; i += gridDim.x * 256) {
        const float4 x4 = p4[i];
        const float4 y4 = t4[i];
        {   const float x = x4.x, y = y4.x;
            const float z = __expf(-fabsf(x));
            const float inv = 1.0f / (1.0f + z);
            sb += fmaxf(x, 0.f) + __logf(1.0f + z) - y * x;
            const float p = (x >= 0.f) ? inv : z * inv;
            sp += p; sy += y; spy += p * y; }
        {   const float x = x4.y, y = y4.y;
            const float z = __expf(-fabsf(x));
            const float inv = 1.0f / (1.0f + z);
            sb += fmaxf(x, 0.f) + __logf(1.0f + z) - y * x;
            const float p = (x >= 0.f) ? inv : z * inv;
            sp += p; sy += y; spy += p * y; }
        {   const float x = x4.z, y = y4.z;
            const float z = __expf(-fabsf(x));
            const float inv = 1.0f / (1.0f + z);
            sb += fmaxf(x, 0.f) + __logf(1.0f + z) - y * x;
            const float p = (x >= 0.f) ? inv : z * inv;
            sp += p; sy += y; spy += p * y; }
        {   const float x = x4.w, y = y4.w;
            const float z = __expf(-fabsf(x));
            const float inv = 1.0f / (1.0f + z);
            sb += fmaxf(x, 0.f) + __logf(1.0f + z) - y * x;
            const float p = (x >= 0.f) ? inv : z * inv;
            sp += p; sy += y; spy += p * y; }
    }
    for (int off = 32; off > 0; off >>= 1) {
        sb  += __shfl_down(sb,  off);
        sp  += __shfl_down(sp,  off);
        sy  += __shfl_down(sy,  off);
        spy += __shfl_down(spy, off);
    }
    __shared__ float rb[4][4];
    const int wid = threadIdx.x >> 6, lane = threadIdx.x & 63;
    if (lane == 0) { rb[wid][0] = sb; rb[wid][1] = sp; rb[wid][2] = sy; rb[wid][3] = spy; }
    __syncthreads();
    if (threadIdx.x == 0) {
        double v0 = 0, v1 = 0, v2 = 0, v3 = 0;
        for (int w = 0; w < 4; ++w) {
            v0 += (double)rb[w][0]; v1 += (double)rb[w][1];
            v2 += (double)rb[w][2]; v3 += (double)rb[w][3];
        }
        const int slot = blockIdx.x & (SLOTS - 1);
        atomicAdd(&acc[slot * 8 + 0], v0);
        atomicAdd(&acc[slot * 8 + 1], v1);
        atomicAdd(&acc[slot * 8 + 2], v2);
        atomicAdd(&acc[slot * 8 + 3], v3);
    }
}

__global__ void zero_acc(double* acc) { acc[threadIdx.x] = 0.0; }

__global__ void finalize_k(const double* __restrict__ acc, float* __restrict__ out)
{
    __shared__ double S[8];
    const int j = threadIdx.x;
    if (j < 8) {
        double t = 0.0;
        for (int k = 0; k < SLOTS; ++k) t += acc[k * 8 + j];
        S[j] = t;
    }
    __syncthreads();
    if (j == 0) {
        const double bce   = S[0] / (double)N_TOT;
        const double dice  = (2.0 * S[3] + 1.0) / (S[1] + S[2] + 1.0);
        const double tprec = (S[5] + 1.0) / (S[4] + 1.0);
        const double tsens = (S[7] + 1.0) / (S[6] + 1.0);
        const double cl    = 2.0 * tprec * tsens / (tprec + tsens + 1e-7);
        out[0] = (float)(0.3 * bce + 0.3 * (1.0 - dice) + 0.4 * (1.0 - cl));
    }
}

// ---------------------------------------------------------------------------
extern "C" void kernel_launch(void* const* d_in, const int* in_sizes, int n_in,
                              void* d_out, int out_size, void* d_ws, size_t ws_size,
                              hipStream_t stream)
{
    const float* pred = (const float*)d_in[0];
    const float* tgt  = (const float*)d_in[1];
    float* out = (float*)d_out;
    double* acc = (double*)d_ws;                 // SLOTS*8 doubles = 2 KB

    zero_acc<<<1, SLOTS * 8, 0, stream>>>(acc);

    bce_dice_reduce<<<1024, 256, 0, stream>>>((const float4*)pred, (const float4*)tgt, acc);

    const dim3 grid(W_IMG / TILE, H_IMG / TILE, N_B);   // (16,16,16)
    // skeleton of p = sigmoid(pred); reduce against y = target
    skel_mega<true,  false, 4><<<grid, 512, 0, stream>>>(pred, tgt,  acc);
    // skeleton of y = target;        reduce against p = sigmoid(pred)
    skel_mega<false, true,  6><<<grid, 512, 0, stream>>>(tgt,  pred, acc);

    finalize_k<<<1, 64, 0, stream>>>(acc, out);
}